// Round 5
// baseline (13.517 us; speedup 1.0000x reference)
//
#include <hip/hip_runtime.h>

#define ORDER 64

typedef _Float16 half8 __attribute__((ext_vector_type(8)));
typedef __fp16 fp16x2 __attribute__((ext_vector_type(2)));
typedef float floatx4 __attribute__((ext_vector_type(4)));

// MFMA formulation, operand-swapped for vectorized stores.
// For each channel d:  h[16*l0 + i] = sum_o W[i,o] * Q[l0,o]
//   Q[l0,o] = R_o*exp(g_o*16*l0),  W[i,o] = exp(g_o*i),  g = -exp(p+gamma)
// MFMA computes C2[m=i, n=l0] with A=W (constant across tiles), B=Q
// (geometric recurrence along l). C/D layout: col=lane&15, row=4*(lane>>4)+reg
// => lane holds h[256*T + 16*c15 + 4*g16 + {0..3}] — one dwordx4 store/tile,
// 1 KB contiguous per wave-instruction.
// R5: block=128 (one d, 2 waves x 8 tiles), grid=D — finer retirement
// granularity so the CP backfills blocks while stores drain; nontemporal
// stores bypass L2 allocate (output is write-once and ~= L2 size).
__global__ __launch_bounds__(128) void imf_mfma(const float* __restrict__ gamma,
                                                const float* __restrict__ R,
                                                const float* __restrict__ p,
                                                float* __restrict__ out) {
    const int tid  = threadIdx.x;
    const int wave = tid >> 6;    // 0..1
    const int lane = tid & 63;
    const int c15  = lane & 15;   // A-row i / C-col
    const int g16  = lane >> 4;   // 0..3

    const int d     = blockIdx.x;
    const int tile0 = wave * 8;

    float wstep[2][8];   // exp(g*256): Q advance per 16-l0 tile
    float q[2][8];       // current Q (f32, converted to f16 per tile)
    half8 Wf[2];         // A operand: W[i=c15, o-slice] (constant)

    const float fc  = (float)c15;
    const float Lr0 = (float)(256 * tile0 + 16 * c15);

#pragma unroll
    for (int h = 0; h < 2; ++h) {
        const int obase = d * ORDER + 32 * h + 8 * g16;
        // vectorized input loads (32B-aligned: obase is a multiple of 8)
        const float4 gv0 = *(const float4*)(gamma + obase);
        const float4 gv1 = *(const float4*)(gamma + obase + 4);
        const float4 pv0 = *(const float4*)(p + obase);
        const float4 pv1 = *(const float4*)(p + obase + 4);
        const float4 rv0 = *(const float4*)(R + obase);
        const float4 rv1 = *(const float4*)(R + obase + 4);
        float gs[8] = {gv0.x, gv0.y, gv0.z, gv0.w, gv1.x, gv1.y, gv1.z, gv1.w};
        float ps[8] = {pv0.x, pv0.y, pv0.z, pv0.w, pv1.x, pv1.y, pv1.z, pv1.w};
        float rs[8] = {rv0.x, rv0.y, rv0.z, rv0.w, rv1.x, rv1.y, rv1.z, rv1.w};
#pragma unroll
        for (int j = 0; j < 8; ++j) {
            const float g = -__expf(gs[j] + ps[j]);   // glogp = -exp(p)*exp(gamma)
            wstep[h][j] = __expf(g * 256.0f);
            q[h][j]     = rs[j] * __expf(g * Lr0);
            Wf[h][j]    = (_Float16)__expf(g * fc);
        }
    }

    // element offset: d*4096 + 256*tile0 + 16*c15 + 4*g16  (16B aligned)
    floatx4* op4 = (floatx4*)(out + ((size_t)d << 12) + 256 * tile0 + 16 * c15 + 4 * g16);

#pragma unroll
    for (int t = 0; t < 8; ++t) {
        half8 Q0, Q1;
#pragma unroll
        for (int j = 0; j < 8; j += 2) {
            fp16x2 p0 = __builtin_amdgcn_cvt_pkrtz(q[0][j], q[0][j + 1]);
            Q0[j]     = (_Float16)p0[0];
            Q0[j + 1] = (_Float16)p0[1];
            fp16x2 p1 = __builtin_amdgcn_cvt_pkrtz(q[1][j], q[1][j + 1]);
            Q1[j]     = (_Float16)p1[0];
            Q1[j + 1] = (_Float16)p1[1];
        }
        floatx4 acc = {0.f, 0.f, 0.f, 0.f};
        acc = __builtin_amdgcn_mfma_f32_16x16x32_f16(Wf[0], Q0, acc, 0, 0, 0);
        acc = __builtin_amdgcn_mfma_f32_16x16x32_f16(Wf[1], Q1, acc, 0, 0, 0);
        // advance Q to next tile (independent of mfma result -> overlaps)
#pragma unroll
        for (int j = 0; j < 8; ++j) {
            q[0][j] *= wstep[0][j];
            q[1][j] *= wstep[1][j];
        }
        __builtin_nontemporal_store(acc, &op4[t * 64]);   // 1 KB/wave-instr, L2-bypass
    }
}

// Generic fallback for any L: one thread per (d, l), direct exp evaluation.
__global__ void imf_generic(const float* __restrict__ gamma,
                            const float* __restrict__ R,
                            const float* __restrict__ p,
                            float* __restrict__ out,
                            int D, int L) {
    const int idx = blockIdx.x * blockDim.x + threadIdx.x;
    const int total = D * L;
    if (idx >= total) return;
    const int d = idx / L;
    const int l = idx - d * L;
    const float lf = (float)l;
    float acc = 0.0f;
    for (int o = 0; o < ORDER; ++o) {
        const int k = d * ORDER + o;
        const float gl = -__expf(p[k] + gamma[k]);
        acc = fmaf(R[k], __expf(gl * lf), acc);
    }
    out[idx] = acc;
}

extern "C" void kernel_launch(void* const* d_in, const int* in_sizes, int n_in,
                              void* d_out, int out_size, void* d_ws, size_t ws_size,
                              hipStream_t stream) {
    // inputs: [0]=L (scalar), [1]=gamma, [2]=R, [3]=p
    const float* gamma = (const float*)d_in[1];
    const float* R = (const float*)d_in[2];
    const float* p = (const float*)d_in[3];
    float* out = (float*)d_out;

    const int D = in_sizes[1] / ORDER;   // 2048
    const int L = out_size / D;          // 4096

    if (L == 4096) {
        imf_mfma<<<dim3(D), dim3(128), 0, stream>>>(gamma, R, p, out);
    } else {
        const int total = D * L;
        imf_generic<<<dim3((total + 255) / 256), dim3(256), 0, stream>>>(gamma, R, p, out, D, L);
    }
}

// Round 6
// 12.837 us; speedup vs baseline: 1.0529x; 1.0529x over previous
//
#include <hip/hip_runtime.h>

#define ORDER 64

typedef _Float16 half8 __attribute__((ext_vector_type(8)));
typedef __fp16 fp16x2 __attribute__((ext_vector_type(2)));
typedef float floatx4 __attribute__((ext_vector_type(4)));

// MFMA formulation, operand-swapped for vectorized stores (best config: R4).
// For each channel d:  h[16*l0 + i] = sum_o W[i,o] * Q[l0,o]
//   Q[l0,o] = R_o*exp(g_o*16*l0),  W[i,o] = exp(g_o*i),  g = -exp(p+gamma)
// MFMA computes C2[m=i, n=l0] with A=W (constant across tiles), B=Q
// (geometric recurrence along l). C/D layout: col=lane&15, row=4*(lane>>4)+reg
// => lane holds h[256*T + 16*c15 + 4*g16 + {0..3}] — one dwordx4 store/tile.
// Stores go through L2 (write-back): nt stores measured +0.5us WORSE (R5).
// Block = 256 threads = 4 waves; waves (0,1)->d0, (2,3)->d1. Grid = D/2.
__global__ __launch_bounds__(256) void imf_mfma(const float* __restrict__ gamma,
                                                const float* __restrict__ R,
                                                const float* __restrict__ p,
                                                float* __restrict__ out) {
    const int tid  = threadIdx.x;
    const int wave = tid >> 6;
    const int lane = tid & 63;
    const int c15  = lane & 15;   // A-row i / C-col
    const int g16  = lane >> 4;   // 0..3

    const int d     = blockIdx.x * 2 + (wave >> 1);
    const int tile0 = (wave & 1) * 8;

    float wstep[2][8];   // exp(g*256): Q advance per 16-l0 tile
    float q[2][8];       // current Q (f32, converted to f16 per tile)
    half8 Wf[2];         // A operand: W[i=c15, o-slice] (constant)

    const float fc  = (float)c15;
    const float Lr0 = (float)(256 * tile0 + 16 * c15);

#pragma unroll
    for (int h = 0; h < 2; ++h) {
        const int obase = d * ORDER + 32 * h + 8 * g16;
        const float4 gv0 = *(const float4*)(gamma + obase);
        const float4 gv1 = *(const float4*)(gamma + obase + 4);
        const float4 pv0 = *(const float4*)(p + obase);
        const float4 pv1 = *(const float4*)(p + obase + 4);
        const float4 rv0 = *(const float4*)(R + obase);
        const float4 rv1 = *(const float4*)(R + obase + 4);
        float gs[8] = {gv0.x, gv0.y, gv0.z, gv0.w, gv1.x, gv1.y, gv1.z, gv1.w};
        float ps[8] = {pv0.x, pv0.y, pv0.z, pv0.w, pv1.x, pv1.y, pv1.z, pv1.w};
        float rs[8] = {rv0.x, rv0.y, rv0.z, rv0.w, rv1.x, rv1.y, rv1.z, rv1.w};
#pragma unroll
        for (int j = 0; j < 8; ++j) {
            const float g = -__expf(gs[j] + ps[j]);   // glogp = -exp(p)*exp(gamma)
            wstep[h][j] = __expf(g * 256.0f);
            q[h][j]     = rs[j] * __expf(g * Lr0);
            Wf[h][j]    = (_Float16)__expf(g * fc);
        }
    }

    // element offset: d*4096 + 256*tile0 + 16*c15 + 4*g16  (16B aligned)
    floatx4* op4 = (floatx4*)(out + ((size_t)d << 12) + 256 * tile0 + 16 * c15 + 4 * g16);

#pragma unroll
    for (int t = 0; t < 8; ++t) {
        half8 Q0, Q1;
#pragma unroll
        for (int j = 0; j < 8; j += 2) {
            fp16x2 p0 = __builtin_amdgcn_cvt_pkrtz(q[0][j], q[0][j + 1]);
            Q0[j]     = (_Float16)p0[0];
            Q0[j + 1] = (_Float16)p0[1];
            fp16x2 p1 = __builtin_amdgcn_cvt_pkrtz(q[1][j], q[1][j + 1]);
            Q1[j]     = (_Float16)p1[0];
            Q1[j + 1] = (_Float16)p1[1];
        }
        floatx4 acc = {0.f, 0.f, 0.f, 0.f};
        acc = __builtin_amdgcn_mfma_f32_16x16x32_f16(Wf[0], Q0, acc, 0, 0, 0);
        acc = __builtin_amdgcn_mfma_f32_16x16x32_f16(Wf[1], Q1, acc, 0, 0, 0);
        // advance Q to next tile (independent of mfma result -> overlaps)
#pragma unroll
        for (int j = 0; j < 8; ++j) {
            q[0][j] *= wstep[0][j];
            q[1][j] *= wstep[1][j];
        }
        op4[t * 64] = acc;   // 1 KB contiguous per wave-instruction, via L2
    }
}

// Generic fallback for any L: one thread per (d, l), direct exp evaluation.
__global__ void imf_generic(const float* __restrict__ gamma,
                            const float* __restrict__ R,
                            const float* __restrict__ p,
                            float* __restrict__ out,
                            int D, int L) {
    const int idx = blockIdx.x * blockDim.x + threadIdx.x;
    const int total = D * L;
    if (idx >= total) return;
    const int d = idx / L;
    const int l = idx - d * L;
    const float lf = (float)l;
    float acc = 0.0f;
    for (int o = 0; o < ORDER; ++o) {
        const int k = d * ORDER + o;
        const float gl = -__expf(p[k] + gamma[k]);
        acc = fmaf(R[k], __expf(gl * lf), acc);
    }
    out[idx] = acc;
}

extern "C" void kernel_launch(void* const* d_in, const int* in_sizes, int n_in,
                              void* d_out, int out_size, void* d_ws, size_t ws_size,
                              hipStream_t stream) {
    // inputs: [0]=L (scalar), [1]=gamma, [2]=R, [3]=p
    const float* gamma = (const float*)d_in[1];
    const float* R = (const float*)d_in[2];
    const float* p = (const float*)d_in[3];
    float* out = (float*)d_out;

    const int D = in_sizes[1] / ORDER;   // 2048
    const int L = out_size / D;          // 4096

    if (L == 4096 && (D & 1) == 0) {
        imf_mfma<<<dim3(D / 2), dim3(256), 0, stream>>>(gamma, R, p, out);
    } else {
        const int total = D * L;
        imf_generic<<<dim3((total + 255) / 256), dim3(256), 0, stream>>>(gamma, R, p, out, D, L);
    }
}